// Round 21
// baseline (3341.098 us; speedup 1.0000x reference)
//
#include <hip/hip_runtime.h>
#include <math.h>

#define S_LEN 2048
#define BATCH 64
#define IN_D  128
#define HID   256
#define G4    1024   // 4*HID

#if defined(__has_builtin)
# if __has_builtin(__builtin_amdgcn_sdot4)
#  define USE_SDOT4 1
# endif
#endif

__device__ __forceinline__ int dot4i8(int a, int b, int c) {
#ifdef USE_SDOT4
    return __builtin_amdgcn_sdot4(a, b, c, false);
#else
    int r = c;
    r += ((a << 24) >> 24) * ((b << 24) >> 24);
    r += ((a << 16) >> 24) * ((b << 16) >> 24);
    r += ((a <<  8) >> 24) * ((b <<  8) >> 24);
    r += ( a        >> 24) * ( b        >> 24);
    return r;
#endif
}

// fake_quant value: clip(round_half_even(x*16), -128, 127)/16 — exact f32 ops
__device__ __forceinline__ float fq4(float x) {
    return fminf(fmaxf(rintf(x * 16.0f), -128.0f), 127.0f) * 0.0625f;
}

// ---------------------------------------------------------------------------
// XLA-CPU JIT exp f32 (VF32Exp, FMA host, contract ON) — bit-frozen from r14.
// ---------------------------------------------------------------------------
__device__ __forceinline__ float exp_vsl(float x) {
    const float xc = fminf(fmaxf(x, -88.3762626647949f), 88.3762626647950f);
    const float fx = floorf(fmaf(xc, 1.44269504088896341f, 0.5f));
    float r = fmaf(-fx, 0.693359375f, xc);
    r = fmaf(fx, 2.12194440e-4f, r);
    const float z = __fmul_rn(r, r);
    float y = fmaf(r, 1.9875691500e-4f, 1.3981999507e-3f);
    y = fmaf(y, r, 8.3334519073e-3f);
    y = fmaf(y, r, 4.1665795894e-2f);
    y = fmaf(y, r, 1.6666665459e-1f);
    y = fmaf(y, r, 5.0000001201e-1f);
    y = fmaf(y, z, r);
    y = __fadd_rn(y, 1.0f);
    const int n = (int)fx;
    const float sc = __int_as_float((n + 127) << 23);
    return __fmul_rn(y, sc);
}

// ---------------------------------------------------------------------------
// XLA-CPU JIT tanh f32 (VF32Tanh): clamp ±9, FMA Horner — bit-frozen from r14.
// ---------------------------------------------------------------------------
__device__ __forceinline__ float tanh_vsl(float x) {
    const float xc = fminf(fmaxf(x, -9.0f), 9.0f);
    const float x2 = __fmul_rn(xc, xc);
    float p = -2.76076847742355e-16f;
    p = fmaf(p, x2, 2.00018790482477e-13f);
    p = fmaf(p, x2, -8.60467152213735e-11f);
    p = fmaf(p, x2, 5.12229709037114e-08f);
    p = fmaf(p, x2, 1.48572235717979e-05f);
    p = fmaf(p, x2, 6.37261928875436e-04f);
    p = fmaf(p, x2, 4.89352455891786e-03f);
    p = __fmul_rn(p, xc);
    float q = 1.19825839466702e-06f;
    q = fmaf(q, x2, 1.18534705686654e-04f);
    q = fmaf(q, x2, 2.26843463243900e-03f);
    q = fmaf(q, x2, 4.89352518554385e-03f);
    return __fdiv_rn(p, q);
}

// XLA LogisticExpander: 1 / (1 + exp(-x)) — bit-frozen.
__device__ __forceinline__ float sig_vsl(float x) {
    const float ef = exp_vsl(-x);
    return __fdiv_rn(1.0f, __fadd_rn(1.0f, ef));
}

// ---------------------------------------------------------------------------
// Prep: wi -> fq fp32; wh -> int8 packed, per-thread-contiguous int4 layout
// whq4[(d>>2)*4096 + row*4 + (d&3)]; biases; zero state. (unchanged from r20)
// ---------------------------------------------------------------------------
__global__ void qlstm_prep(const float* __restrict__ wih, const float* __restrict__ whh,
                           const float* __restrict__ bih, const float* __restrict__ bhh,
                           float* __restrict__ wiq, int* __restrict__ whq4,
                           float* __restrict__ biq, float* __restrict__ bhq,
                           float* __restrict__ c_state, int* __restrict__ hq_state) {
    const int idx = blockIdx.x * 256 + threadIdx.x;
    if (idx < G4 * IN_D) wiq[idx] = fq4(wih[idx]);
    if (idx < (HID / 4) * G4) {
        const int d = idx >> 10;         // k-group 0..63
        const int j = idx & 1023;        // gate row
        int pack = 0;
#pragma unroll
        for (int c = 0; c < 4; ++c) {
            const int k = d * 4 + c;
            float q = fminf(fmaxf(rintf(whh[j * HID + k] * 16.0f), -128.0f), 127.0f);
            int qi = (int)q;
            pack |= (qi & 0xff) << (8 * c);
        }
        whq4[(d >> 2) * 4096 + j * 4 + (d & 3)] = pack;
    }
    if (idx < G4) { biq[idx] = fq4(bih[idx]); bhq[idx] = fq4(bhh[idx]); }
    if (idx < BATCH * HID) c_state[idx] = 0.0f;
    if (idx < BATCH * (HID / 4)) hq_state[idx] = 0;
}

// ---------------------------------------------------------------------------
// Standalone GEMM (prologue): UNFUSED acc=add(acc,mul) ascending k (r14 bits).
// GPAD 129: staging-write stride 516%32=4 -> 4-way (was 16-way at 132).
// ---------------------------------------------------------------------------
#define GPAD 129
__global__ __launch_bounds__(256, 1) void qlstm_gx(
    const float* __restrict__ X, const float* __restrict__ Wq,
    const float* __restrict__ biq, float* __restrict__ Gx, int Mc) {
    __shared__ float Xs[IN_D][GPAD];
    __shared__ float Ws[IN_D][GPAD];
    const int t  = threadIdx.x;
    const int m0 = blockIdx.x * 128;
    const int n0 = blockIdx.y * 128;

#pragma unroll
    for (int i = 0; i < 16; ++i) {
        const int flat = i * 256 + t;
        const int m  = flat >> 5;
        const int k4 = flat & 31;
        float4 v = make_float4(0.f, 0.f, 0.f, 0.f);
        if (m0 + m < Mc) v = *(const float4*)(X + (size_t)(m0 + m) * IN_D + k4 * 4);
        Xs[k4 * 4 + 0][m] = v.x; Xs[k4 * 4 + 1][m] = v.y;
        Xs[k4 * 4 + 2][m] = v.z; Xs[k4 * 4 + 3][m] = v.w;
        float4 w = *(const float4*)(Wq + (size_t)(n0 + m) * IN_D + k4 * 4);
        Ws[k4 * 4 + 0][m] = w.x; Ws[k4 * 4 + 1][m] = w.y;
        Ws[k4 * 4 + 2][m] = w.z; Ws[k4 * 4 + 3][m] = w.w;
    }
    __syncthreads();

    const int tx = t & 15, ty = t >> 4;
    float acc[8][8];
#pragma unroll
    for (int i = 0; i < 8; ++i)
#pragma unroll
        for (int j = 0; j < 8; ++j) acc[i][j] = 0.0f;

#pragma unroll 4
    for (int k = 0; k < IN_D; ++k) {
        float4 a0 = *(const float4*)&Xs[k][ty * 8];
        float4 a1 = *(const float4*)&Xs[k][ty * 8 + 4];
        float4 b0 = *(const float4*)&Ws[k][tx * 8];
        float4 b1 = *(const float4*)&Ws[k][tx * 8 + 4];
        const float a[8]  = {a0.x, a0.y, a0.z, a0.w, a1.x, a1.y, a1.z, a1.w};
        const float bb[8] = {b0.x, b0.y, b0.z, b0.w, b1.x, b1.y, b1.z, b1.w};
#pragma unroll
        for (int i = 0; i < 8; ++i)
#pragma unroll
            for (int j = 0; j < 8; ++j)
                acc[i][j] = __fadd_rn(acc[i][j], __fmul_rn(a[i], bb[j]));   // UNFUSED
    }

    float4 bv0 = *(const float4*)(biq + n0 + tx * 8);
    float4 bv1 = *(const float4*)(biq + n0 + tx * 8 + 4);
    const float bb[8] = {bv0.x, bv0.y, bv0.z, bv0.w, bv1.x, bv1.y, bv1.z, bv1.w};
#pragma unroll
    for (int i = 0; i < 8; ++i) {
        const int m = m0 + ty * 8 + i;
        if (m < Mc) {
            float o[8];
#pragma unroll
            for (int j = 0; j < 8; ++j) o[j] = __fadd_rn(acc[i][j], bb[j]);
            *(float4*)(Gx + (size_t)m * G4 + n0 + tx * 8)     = make_float4(o[0], o[1], o[2], o[3]);
            *(float4*)(Gx + (size_t)m * G4 + n0 + tx * 8 + 4) = make_float4(o[4], o[5], o[6], o[7]);
        }
    }
}

// ---------------------------------------------------------------------------
// Fused pipeline kernel, 256 blocks x 512 threads (LDS 132KB -> 1 block/CU,
// 2 waves/SIMD -> 256-VGPR budget so scan weights can be register-resident):
//   blocks 0..63   : scan chunk k (2 gate rows/thread: t and t+512 — halves
//                    the hq LDS-broadcast data, the measured bottleneck)
//   blocks 64..255 : GEMM chunk k+1
// All f32 arithmetic bit-identical to the r14 stack.
// ---------------------------------------------------------------------------
__attribute__((amdgpu_waves_per_eu(2)))
__global__ __launch_bounds__(512) void qlstm_fused(
    const float* __restrict__ Gx_rd, float* __restrict__ Gx_wr,
    const float* __restrict__ Xn, const float* __restrict__ Wq,
    const float* __restrict__ biq, int Mc_next,
    const int* __restrict__ whq4, const float* __restrict__ bhq,
    float* __restrict__ out, float* __restrict__ c_state, int* __restrict__ hq_state,
    float* __restrict__ hn, float* __restrict__ cn, int s0, int CHc) {
    const int t = threadIdx.x;
    __shared__ __align__(16) char smem[2 * IN_D * GPAD * 4];   // 132096 B

    if (blockIdx.x < 64) {
        // ------------------------- scan role -------------------------
        const int b = blockIdx.x;
        int*    hqb = (int*)smem;                 // [2][64]
        float2* fo  = (float2*)(smem + 512);      // [256]

        const int4* __restrict__ wq4 = (const int4*)whq4;
        int4 wlo[16], whi[16];
#pragma unroll
        for (int j = 0; j < 16; ++j) {
            wlo[j] = wq4[j * 1024 + t];
            whi[j] = wq4[j * 1024 + t + 512];
        }

        const float bh0 = bhq[t];
        const float bh1 = bhq[t + 512];

        float creg = 0.0f;
        if (t < HID) creg = c_state[b * HID + t];
        if (t < 64)  hqb[t] = hq_state[b * 64 + t];
        __syncthreads();

        float gx0 = Gx_rd[(size_t)b * G4 + t];
        float gx1 = Gx_rd[(size_t)b * G4 + t + 512];

        for (int sl = 0; sl < CHc; ++sl) {
            const int p = sl & 1;
            float nx0 = 0.0f, nx1 = 0.0f;
            if (sl + 1 < CHc) {
                const size_t base = (size_t)((sl + 1) * BATCH + b) * G4;
                nx0 = Gx_rd[base + t];
                nx1 = Gx_rd[base + t + 512];
            }

            const int4* __restrict__ hv4 = (const int4*)(hqb + p * 64);
            int ca0 = 0, ca1 = 0, ca2 = 0, ca3 = 0;
            int cb0 = 0, cb1 = 0, cb2 = 0, cb3 = 0;
#pragma unroll
            for (int j = 0; j < 4; ++j) {
                const int4 hv = hv4[j];
                ca0 = dot4i8(wlo[j].x, hv.x, ca0); ca0 = dot4i8(wlo[j].y, hv.y, ca0);
                ca0 = dot4i8(wlo[j].z, hv.z, ca0); ca0 = dot4i8(wlo[j].w, hv.w, ca0);
                cb0 = dot4i8(whi[j].x, hv.x, cb0); cb0 = dot4i8(whi[j].y, hv.y, cb0);
                cb0 = dot4i8(whi[j].z, hv.z, cb0); cb0 = dot4i8(whi[j].w, hv.w, cb0);
            }
#pragma unroll
            for (int j = 4; j < 8; ++j) {
                const int4 hv = hv4[j];
                ca1 = dot4i8(wlo[j].x, hv.x, ca1); ca1 = dot4i8(wlo[j].y, hv.y, ca1);
                ca1 = dot4i8(wlo[j].z, hv.z, ca1); ca1 = dot4i8(wlo[j].w, hv.w, ca1);
                cb1 = dot4i8(whi[j].x, hv.x, cb1); cb1 = dot4i8(whi[j].y, hv.y, cb1);
                cb1 = dot4i8(whi[j].z, hv.z, cb1); cb1 = dot4i8(whi[j].w, hv.w, cb1);
            }
#pragma unroll
            for (int j = 8; j < 12; ++j) {
                const int4 hv = hv4[j];
                ca2 = dot4i8(wlo[j].x, hv.x, ca2); ca2 = dot4i8(wlo[j].y, hv.y, ca2);
                ca2 = dot4i8(wlo[j].z, hv.z, ca2); ca2 = dot4i8(wlo[j].w, hv.w, ca2);
                cb2 = dot4i8(whi[j].x, hv.x, cb2); cb2 = dot4i8(whi[j].y, hv.y, cb2);
                cb2 = dot4i8(whi[j].z, hv.z, cb2); cb2 = dot4i8(whi[j].w, hv.w, cb2);
            }
#pragma unroll
            for (int j = 12; j < 16; ++j) {
                const int4 hv = hv4[j];
                ca3 = dot4i8(wlo[j].x, hv.x, ca3); ca3 = dot4i8(wlo[j].y, hv.y, ca3);
                ca3 = dot4i8(wlo[j].z, hv.z, ca3); ca3 = dot4i8(wlo[j].w, hv.w, ca3);
                cb3 = dot4i8(whi[j].x, hv.x, cb3); cb3 = dot4i8(whi[j].y, hv.y, cb3);
                cb3 = dot4i8(whi[j].z, hv.z, cb3); cb3 = dot4i8(whi[j].w, hv.w, cb3);
            }
            const int accl = (ca0 + ca1) + (ca2 + ca3);
            const int acch = (cb0 + cb1) + (cb2 + cb3);

            const float hh0 = (float)accl * 0.00390625f;   // exact multiple of 2^-8
            const float hh1 = (float)acch * 0.00390625f;
            const float gate0 = __fadd_rn(__fadd_rn(gx0, hh0), bh0);
            const float gate1 = __fadd_rn(__fadd_rn(gx1, hh1), bh1);

            float tv0, tv1;                                // wave-uniform branches
            if (t < HID) {                                 // rows: i (t), g (t+512)
                tv0 = sig_vsl(gate0);
                tv1 = tanh_vsl(gate1);
            } else {                                       // rows: f (t), o (t+512)
                tv0 = sig_vsl(gate0);
                tv1 = sig_vsl(gate1);
                fo[t - HID] = make_float2(tv0, tv1);
            }
            __syncthreads();

            if (t < HID) {
                const float2 f_o = fo[t];
                const float cq = fminf(fmaxf(rintf(__fmul_rn(creg, 16.0f)), -128.0f), 127.0f) * 0.0625f;
                const float c1 = fmaf(f_o.x, cq, __fmul_rn(tv0, tv1));   // contracted (r14)
                const float h1 = __fmul_rn(f_o.y, tanh_vsl(c1));
                creg = c1;
                out[(size_t)((s0 + sl) * BATCH + b) * HID + t] = h1;
                const int hb = (int)fminf(fmaxf(rintf(__fmul_rn(h1, 16.0f)), -128.0f), 127.0f);
                ((signed char*)(hqb + (p ^ 1) * 64))[t] = (signed char)hb;
                if (s0 + sl == S_LEN - 1) {
                    hn[b * HID + t] = h1;
                    cn[b * HID + t] = c1;
                }
            }
            __syncthreads();
            gx0 = nx0; gx1 = nx1;
        }

        if (t < 64)  hq_state[b * 64 + t] = hqb[(CHc & 1) * 64 + t];
        if (t < HID) c_state[b * HID + t] = creg;
    } else if (Mc_next > 0) {
        // ------------------------- gemm role -------------------------
        float (*Xs)[GPAD] = (float(*)[GPAD])smem;
        float (*Ws)[GPAD] = (float(*)[GPAD])(smem + IN_D * GPAD * 4);
        const int wid = blockIdx.x - 64;                   // 0..191
        const int tiles_m = (Mc_next + 127) / 128;
        const int total = tiles_m * 8;
        const int tx = t & 31, ty = t >> 5;                // 32 x 16 thread grid

        for (int tile = wid; tile < total; tile += 192) {
            const int m0 = (tile >> 3) * 128;
            const int n0 = (tile & 7) * 128;

#pragma unroll
            for (int i = 0; i < 8; ++i) {
                const int flat = i * 512 + t;              // 0..4095
                const int m  = flat >> 5;                  // 0..127
                const int k4 = flat & 31;
                float4 v = make_float4(0.f, 0.f, 0.f, 0.f);
                if (m0 + m < Mc_next) v = *(const float4*)(Xn + (size_t)(m0 + m) * IN_D + k4 * 4);
                Xs[k4 * 4 + 0][m] = v.x; Xs[k4 * 4 + 1][m] = v.y;
                Xs[k4 * 4 + 2][m] = v.z; Xs[k4 * 4 + 3][m] = v.w;
                float4 w = *(const float4*)(Wq + (size_t)(n0 + m) * IN_D + k4 * 4);
                Ws[k4 * 4 + 0][m] = w.x; Ws[k4 * 4 + 1][m] = w.y;
                Ws[k4 * 4 + 2][m] = w.z; Ws[k4 * 4 + 3][m] = w.w;
            }
            __syncthreads();

            float acc[8][4];
#pragma unroll
            for (int i = 0; i < 8; ++i)
#pragma unroll
                for (int j = 0; j < 4; ++j) acc[i][j] = 0.0f;

#pragma unroll 4
            for (int k = 0; k < IN_D; ++k) {
                float4 a0 = *(const float4*)&Xs[k][ty * 8];
                float4 a1 = *(const float4*)&Xs[k][ty * 8 + 4];
                float4 bv = *(const float4*)&Ws[k][tx * 4];
                const float a[8]  = {a0.x, a0.y, a0.z, a0.w, a1.x, a1.y, a1.z, a1.w};
                const float bb[4] = {bv.x, bv.y, bv.z, bv.w};
#pragma unroll
                for (int i = 0; i < 8; ++i)
#pragma unroll
                    for (int j = 0; j < 4; ++j)
                        acc[i][j] = __fadd_rn(acc[i][j], __fmul_rn(a[i], bb[j]));  // UNFUSED
            }

            float4 bv = *(const float4*)(biq + n0 + tx * 4);
            const float bb[4] = {bv.x, bv.y, bv.z, bv.w};
#pragma unroll
            for (int i = 0; i < 8; ++i) {
                const int m = m0 + ty * 8 + i;
                if (m < Mc_next) {
                    float o[4];
#pragma unroll
                    for (int j = 0; j < 4; ++j) o[j] = __fadd_rn(acc[i][j], bb[j]);
                    *(float4*)(Gx_wr + (size_t)m * G4 + n0 + tx * 4) = make_float4(o[0], o[1], o[2], o[3]);
                }
            }
            __syncthreads();
        }
    }
}

// ---------------------------------------------------------------------------
// Host side: prep -> prologue GEMM(chunk0) -> fused launches (scan k || gemm k+1)
// ---------------------------------------------------------------------------
extern "C" void kernel_launch(void* const* d_in, const int* in_sizes, int n_in,
                              void* d_out, int out_size, void* d_ws, size_t ws_size,
                              hipStream_t stream) {
    (void)in_sizes; (void)n_in; (void)out_size;
    const float* x   = (const float*)d_in[0];
    const float* wih = (const float*)d_in[1];
    const float* whh = (const float*)d_in[2];
    const float* bih = (const float*)d_in[3];
    const float* bhh = (const float*)d_in[4];

    float* out = (float*)d_out;
    float* hn  = out + (size_t)S_LEN * BATCH * HID;
    float* cn  = hn + (size_t)BATCH * HID;

    char* ws = (char*)d_ws;
    const size_t off_wiq  = 0;                        // 524288
    const size_t off_biq  = off_wiq  + 524288;        // 4096
    const size_t off_bhq  = off_biq  + 4096;          // 4096
    const size_t off_c    = off_bhq  + 4096;          // 65536
    const size_t off_hq   = off_c    + 65536;         // 16384
    const size_t off_whq4 = off_hq   + 16384;         // 262144
    const size_t off_gx   = off_whq4 + 262144;

    float* wiq     = (float*)(ws + off_wiq);
    float* biq     = (float*)(ws + off_biq);
    float* bhq     = (float*)(ws + off_bhq);
    float* c_state = (float*)(ws + off_c);
    int*   hq_st   = (int*)  (ws + off_hq);
    int*   whq4    = (int*)  (ws + off_whq4);
    float* gxbase  = (float*)(ws + off_gx);

    const size_t per_step = (size_t)BATCH * G4 * 4;   // 256KB per time step
    size_t avail = (ws_size > off_gx) ? (ws_size - off_gx) : 0;
    int CH = (int)(avail / (2 * per_step));
    if (CH > 256) CH = 256;
    if (CH < 1) CH = 1;
    float* gxb[2] = { gxbase, gxbase + (size_t)CH * BATCH * G4 };

    qlstm_prep<<<512, 256, 0, stream>>>(wih, whh, bih, bhh, wiq, whq4, biq, bhq, c_state, hq_st);

    // prologue: GEMM chunk 0 (full device)
    const int CHc0 = (S_LEN < CH) ? S_LEN : CH;
    const int Mc0  = CHc0 * BATCH;
    {
        dim3 grid((Mc0 + 127) / 128, G4 / 128);
        qlstm_gx<<<grid, 256, 0, stream>>>(x, wiq, biq, gxb[0], Mc0);
    }

    int k = 0;
    for (int s0 = 0; s0 < S_LEN; s0 += CH, ++k) {
        const int CHc = (S_LEN - s0 < CH) ? (S_LEN - s0) : CH;
        const int ns0 = s0 + CHc;
        const int Mc_next = (ns0 < S_LEN) ? (((S_LEN - ns0 < CH) ? (S_LEN - ns0) : CH) * BATCH) : 0;
        qlstm_fused<<<256, 512, 0, stream>>>(
            gxb[k & 1], gxb[(k + 1) & 1],
            x + (size_t)ns0 * BATCH * IN_D, wiq, biq, Mc_next,
            whq4, bhq, out, c_state, hq_st, hn, cn, s0, CHc);
    }
}